// Round 1
// baseline (361.957 us; speedup 1.0000x reference)
//
#include <hip/hip_runtime.h>
#include <math.h>

typedef __bf16 bf16;
typedef __bf16 bf16x4 __attribute__((ext_vector_type(4)));
typedef __bf16 bf16x8 __attribute__((ext_vector_type(8)));
typedef float f32x4 __attribute__((ext_vector_type(4)));

#define MODE_QKV    0
#define MODE_SCORES 1
#define MODE_PV     2

__device__ inline void gload_lds16(const bf16* g, bf16* l) {
    __builtin_amdgcn_global_load_lds(
        (const __attribute__((address_space(1))) void*)g,
        (__attribute__((address_space(3))) void*)l, 16, 0, 0);
}

// NT GEMM, 256xBN tile, BK=32, 8 waves (2x4), MFMA 16x16x32.
// Counted-vmcnt phased pipeline (T2+T3+T4+T5):
//  - 4-slot LDS ring: tile t lives in slot t&3; tile t+3 is staged (async
//    global_load_lds) during iteration t into slot (t+3)&3 == (t-1)&3, whose
//    reads finished at iteration t-1 (phase-end barrier separates). No
//    read/write overlap by construction.
//  - raw s_barrier (no implicit vmcnt(0) drain); per-tile s_waitcnt
//    vmcnt(2*LPT) guarantees tile t+1 landed while leaving tiles t+2,t+3 in
//    flight. Tail drains 2L -> L -> 0.
//  - 2 phases per K-tile (m-half each): {stage || ds_read frags} barrier
//    setprio(1) MFMA-cluster setprio(0) barrier.  B frags read once in ph0,
//    reused in ph1.
//  - LDS chunk-XOR swizzle (proven, 0 bank conflicts): slot q of row r holds
//    global 16B chunk q ^ ((r>>1)&3).
// MODE_QKV:    C = bf16(acc + bias[col])
// MODE_SCORES: C = bf16(exp(alpha*acc))
// MODE_PV:     C = fp32 acc
template <int MODE, int BN>
__global__ __launch_bounds__(512) void mfma_nt8(
    const bf16* __restrict__ A, const bf16* __restrict__ B,
    const float* __restrict__ bias, void* __restrict__ Cv,
    int K, int lda, int ldb, int ldc,
    long sA, long sB, long sC, float alpha)
{
    constexpr int BM  = 256, BK = 32;
    constexpr int WN  = BN / 4;          // per-wave col width (64 or 32)
    constexpr int NJ  = WN / 16;         // n-frags per wave (4 or 2)
    constexpr int LB  = (BN == 256) ? 2 : 1;  // B loads/thread/tile
    constexpr int LPT = 2 + LB;          // loads/thread/tile total

    A += (long)blockIdx.z * sA;
    B += (long)blockIdx.z * sB;

    __shared__ bf16 As[4 * BM * BK] __attribute__((aligned(16)));
    __shared__ bf16 Bs[4 * BN * BK] __attribute__((aligned(16)));

    const int t    = threadIdx.x;
    const int m0   = blockIdx.y * BM;
    const int n0   = blockIdx.x * BN;
    const int lane = t & 63;
    const int wave = t >> 6;
    const int wr   = (wave >> 2) * 128;  // wave row origin in tile
    const int wc   = (wave & 3) * WN;    // wave col origin in tile
    const int fr   = lane & 15;
    const int kq8  = lane >> 4;          // which 8-k chunk this lane wants

    // cooperative staging decomposition: chunk c -> row c>>2, slot c&3,
    // global k8-chunk = slot ^ ((row>>1)&3)
    const int ra0 = t >> 2,         qa0 = t & 3;
    const int ra1 = (t + 512) >> 2, qa1 = (t + 512) & 3;
    const int ga0 = (qa0 ^ ((ra0 >> 1) & 3)) * 8;
    const int ga1 = (qa1 ^ ((ra1 >> 1) & 3)) * 8;

    const bf16* gA0 = A + (long)(m0 + ra0) * lda + ga0;
    const bf16* gA1 = A + (long)(m0 + ra1) * lda + ga1;
    const bf16* gB0 = B + (long)(n0 + ra0) * ldb + ga0;
    const bf16* gB1 = B + (long)(n0 + ((LB == 2) ? ra1 : ra0)) * ldb
                        + ((LB == 2) ? ga1 : ga0);

    // per-thread LDS fragment offsets (element units), swizzle folded in
    int offA[8], offB[NJ];
#pragma unroll
    for (int i = 0; i < 8; i++) {
        const int r = wr + i * 16 + fr;
        offA[i] = (r * 4 + (kq8 ^ ((r >> 1) & 3))) * 8;
    }
#pragma unroll
    for (int j = 0; j < NJ; j++) {
        const int r = wc + j * 16 + fr;
        offB[j] = (r * 4 + (kq8 ^ ((r >> 1) & 3))) * 8;
    }

    const int NT = K / BK;

#define STAGE_A(tt) do {                                                   \
    const int  _s = (tt) & 3; const long _k = (long)(tt) * BK;             \
    gload_lds16(gA0 + _k, &As[_s * BM * BK + t * 8]);                      \
    gload_lds16(gA1 + _k, &As[_s * BM * BK + (t + 512) * 8]);              \
} while (0)

#define STAGE_B(tt) do {                                                   \
    const int  _s = (tt) & 3; const long _k = (long)(tt) * BK;             \
    gload_lds16(gB0 + _k, &Bs[_s * BN * BK + t * 8]);                      \
    if constexpr (LB == 2)                                                 \
        gload_lds16(gB1 + _k, &Bs[_s * BN * BK + (t + 512) * 8]);          \
} while (0)

    f32x4 acc[8][NJ] = {};

    // prologue: 3 tiles in flight; force tile 0 landed, leave 1,2 outstanding
    STAGE_A(0); STAGE_B(0);
    STAGE_A(1); STAGE_B(1);
    STAGE_A(2); STAGE_B(2);
    asm volatile("s_waitcnt vmcnt(%0)" :: "i"(2 * LPT) : "memory");
    __builtin_amdgcn_s_barrier();

    for (int tt = 0; tt < NT; ++tt) {
        const bf16* as = &As[(tt & 3) * BM * BK];
        const bf16* bs = &Bs[(tt & 3) * BN * BK];
        bf16x8 af[4], bfr[NJ];

        // ---- phase 0: stage A(t+3); read A-half0 + all B; MFMA half0 ----
        if (tt + 3 < NT) STAGE_A(tt + 3);
#pragma unroll
        for (int i = 0; i < 4; i++) af[i] = *(const bf16x8*)&as[offA[i]];
#pragma unroll
        for (int j = 0; j < NJ; j++) bfr[j] = *(const bf16x8*)&bs[offB[j]];
        asm volatile("" ::: "memory");
        __builtin_amdgcn_s_barrier();
        __builtin_amdgcn_s_setprio(1);
#pragma unroll
        for (int i = 0; i < 4; i++)
#pragma unroll
            for (int j = 0; j < NJ; j++)
                acc[i][j] = __builtin_amdgcn_mfma_f32_16x16x32_bf16(
                    af[i], bfr[j], acc[i][j], 0, 0, 0);
        __builtin_amdgcn_s_setprio(0);
        asm volatile("" ::: "memory");
        __builtin_amdgcn_s_barrier();

        // ---- phase 1: stage B(t+3); read A-half1; MFMA half1 (B reused) --
        if (tt + 3 < NT) STAGE_B(tt + 3);
#pragma unroll
        for (int i = 0; i < 4; i++) af[i] = *(const bf16x8*)&as[offA[4 + i]];
        asm volatile("" ::: "memory");
        __builtin_amdgcn_s_barrier();
        __builtin_amdgcn_s_setprio(1);
#pragma unroll
        for (int i = 0; i < 4; i++)
#pragma unroll
            for (int j = 0; j < NJ; j++)
                acc[4 + i][j] = __builtin_amdgcn_mfma_f32_16x16x32_bf16(
                    af[i], bfr[j], acc[4 + i][j], 0, 0, 0);
        __builtin_amdgcn_s_setprio(0);
        // tile-end counted wait: tile t+1 must be landed; t+2,t+3 may fly.
        if (tt < NT - 3)
            asm volatile("s_waitcnt vmcnt(%0)" :: "i"(2 * LPT) : "memory");
        else if (tt == NT - 3)
            asm volatile("s_waitcnt vmcnt(%0)" :: "i"(LPT) : "memory");
        else if (tt == NT - 2)
            asm volatile("s_waitcnt vmcnt(0)" ::: "memory");
        __builtin_amdgcn_s_barrier();
    }
#undef STAGE_A
#undef STAGE_B

    // C/D layout: col=lane&15, row=(lane>>4)*4+reg  [m89-verified]
    const int r4 = (lane >> 4) * 4;
    if constexpr (MODE == MODE_PV) {
        float* C = (float*)Cv + (long)blockIdx.z * sC;
#pragma unroll
        for (int j = 0; j < NJ; j++) {
            const int col = n0 + wc + j * 16 + fr;
#pragma unroll
            for (int I = 0; I < 8; I++)
#pragma unroll
                for (int r = 0; r < 4; r++) {
                    const long row = m0 + wr + I * 16 + r4 + r;
                    C[row * ldc + col] = acc[I][j][r];
                }
        }
    } else {
        bf16* C = (bf16*)Cv + (long)blockIdx.z * sC;
#pragma unroll
        for (int j = 0; j < NJ; j++) {
            const int col = n0 + wc + j * 16 + fr;
            const float bv = (MODE == MODE_QKV) ? bias[col] : 0.f;
#pragma unroll
            for (int I = 0; I < 8; I++)
#pragma unroll
                for (int r = 0; r < 4; r++) {
                    const long row = m0 + wr + I * 16 + r4 + r;
                    float v = acc[I][j][r];
                    if constexpr (MODE == MODE_QKV)
                        C[row * ldc + col] = (bf16)(v + bv);
                    else
                        C[row * ldc + col] = (bf16)__expf(alpha * v);
                }
        }
    }
}

__global__ __launch_bounds__(256) void f32_to_bf16(
    const float* __restrict__ in, bf16* __restrict__ out, long n)
{
    long i = ((long)blockIdx.x * 256 + threadIdx.x) * 4;
    if (i < n) {
        float4 v = *(const float4*)(in + i);
        bf16x4 o = { (bf16)v.x, (bf16)v.y, (bf16)v.z, (bf16)v.w };
        *(bf16x4*)(out + i) = o;
    }
}

// Vt[b][e][s] = V[b][s][e]; V has ld 3072 (inside qkv), Vt ld 2048.
__global__ __launch_bounds__(256) void transpose_v(
    const bf16* __restrict__ V, bf16* __restrict__ Vt)
{
    __shared__ bf16 tile[32][33];
    const bf16* Vb  = V  + (long)blockIdx.z * 2048 * 3072;
    bf16*       Vtb = Vt + (long)blockIdx.z * 1024 * 2048;
    const int s0 = blockIdx.x * 32, e0 = blockIdx.y * 32;
    const int tx = threadIdx.x & 31, ty = threadIdx.x >> 5;
#pragma unroll
    for (int i = 0; i < 32; i += 8)
        tile[ty + i][tx] = Vb[(long)(s0 + ty + i) * 3072 + e0 + tx];
    __syncthreads();
#pragma unroll
    for (int i = 0; i < 32; i += 8)
        Vtb[(long)(e0 + ty + i) * 2048 + s0 + tx] = tile[tx][ty + i];
}

// Per row: sum exp-scores, write fp32 out1 = Pu/l, renormalize Pu IN PLACE (bf16).
__global__ __launch_bounds__(256) void norm_rows(
    bf16* __restrict__ Pu, float* __restrict__ out1)
{
    bf16* p  = Pu   + (long)blockIdx.x * 2048;
    float* o = out1 + (long)blockIdx.x * 2048;
    const int t = threadIdx.x;
    bf16x8 v = *(const bf16x8*)(p + t * 8);
    float f[8];
    float s = 0.f;
#pragma unroll
    for (int k = 0; k < 8; k++) { f[k] = (float)v[k]; s += f[k]; }
#pragma unroll
    for (int off = 32; off > 0; off >>= 1) s += __shfl_xor(s, off);
    __shared__ float red[4];
    const int wid = t >> 6, lane = t & 63;
    if (lane == 0) red[wid] = s;
    __syncthreads();
    s = red[0] + red[1] + red[2] + red[3];
    const float inv = 1.0f / s;
    float4 a, b;
    a.x = f[0] * inv; a.y = f[1] * inv; a.z = f[2] * inv; a.w = f[3] * inv;
    b.x = f[4] * inv; b.y = f[5] * inv; b.z = f[6] * inv; b.w = f[7] * inv;
    *(float4*)(o + t * 8)     = a;
    *(float4*)(o + t * 8 + 4) = b;
    bf16x8 w;
#pragma unroll
    for (int k = 0; k < 8; k++) w[k] = (bf16)(f[k] * inv);
    *(bf16x8*)(p + t * 8) = w;
}

extern "C" void kernel_launch(void* const* d_in, const int* in_sizes, int n_in,
                              void* d_out, int out_size, void* d_ws, size_t ws_size,
                              hipStream_t stream)
{
    const int B = 4, S = 2048, E = 1024;
    const float* X    = (const float*)d_in[0];   // [B,S,E]
    const float* W    = (const float*)d_in[1];   // [3E,E]
    const float* bias = (const float*)d_in[2];   // [3E]

    float* out0 = (float*)d_out;                  // [B,S,E]
    float* out1 = out0 + (long)B * S * E;         // [B,S,S]

    // ws layout (bytes):
    //   [ 0M, 48M)  qkvb bf16 [B*S, 3072]
    //   [48M, 64M)  Vt   bf16 [B][E][S]
    //   [64M, 96M)  Pu   bf16 [B][S][S]  (exp-scores; renormalized in place)
    //   Xb [64M,80M) and Wb [80M,86.3M) overlap Pu — dead before Pu is written.
    char* ws = (char*)d_ws;
    bf16* qkvb = (bf16*)(ws);
    bf16* Vt   = (bf16*)(ws + 50331648);
    bf16* Pu   = (bf16*)(ws + 67108864);
    bf16* Xb   = (bf16*)(ws + 67108864);
    bf16* Wb   = (bf16*)(ws + 83886080);

    f32_to_bf16<<<(long)B * S * E / 1024, 256, 0, stream>>>(X, Xb, (long)B * S * E);
    f32_to_bf16<<<(long)3 * E * E / 1024, 256, 0, stream>>>(W, Wb, (long)3 * E * E);

    // qkvb = bf16(X @ W^T + b)   [M=8192, N=3072, K=1024] -> 768 blocks (3/CU)
    mfma_nt8<MODE_QKV, 128><<<dim3(3 * E / 128, B * S / 256, 1), 512, 0, stream>>>(
        Xb, Wb, bias, qkvb, E, E, E, 3 * E, 0, 0, 0, 1.0f);

    // Vt = V^T per batch
    transpose_v<<<dim3(S / 32, E / 32, B), 256, 0, stream>>>(qkvb + 2 * E, Vt);

    // Pu = bf16(exp(Q @ K^T / 32))  [2048x2048, K=1024] x4 -> 256 blocks (1/CU)
    mfma_nt8<MODE_SCORES, 256><<<dim3(S / 256, S / 256, B), 512, 0, stream>>>(
        qkvb, qkvb + E, nullptr, Pu, E, 3 * E, 3 * E, S,
        (long)S * 3 * E, (long)S * 3 * E, (long)S * S, 0.03125f);

    // out1 = Pu / rowsum  (fp32); Pu <- normalized bf16 in place
    norm_rows<<<B * S, 256, 0, stream>>>(Pu, out1);

    // out0 = P @ V  (= Pu @ Vt^T, NT)  [2048x1024, K=2048] x4 -> 256 blocks (1/CU)
    mfma_nt8<MODE_PV, 128><<<dim3(E / 128, S / 256, B), 512, 0, stream>>>(
        Pu, Vt, nullptr, out0, S, S, S, E,
        (long)S * S, (long)E * S, (long)S * E, 1.0f);
}

// Round 2
// 312.278 us; speedup vs baseline: 1.1591x; 1.1591x over previous
//
#include <hip/hip_runtime.h>
#include <math.h>

typedef __bf16 bf16;
typedef __bf16 bf16x4 __attribute__((ext_vector_type(4)));
typedef __bf16 bf16x8 __attribute__((ext_vector_type(8)));
typedef float f32x4 __attribute__((ext_vector_type(4)));

#define MODE_QKV    0
#define MODE_SCORES 1
#define MODE_PV     2

__device__ inline void gload_lds16(const bf16* g, bf16* l) {
    __builtin_amdgcn_global_load_lds(
        (const __attribute__((address_space(1))) void*)g,
        (__attribute__((address_space(3))) void*)l, 16, 0, 0);
}

// Inline-asm LDS read: invisible to the compiler's waitcnt inserter, so the
// DMA-alias logic cannot inject vmcnt(0) drains before it. We supply the
// lgkmcnt waits manually (+ sched_barrier per rule 18).
__device__ inline bf16x8 ds_read16(const bf16* p) {
    bf16x8 r;
    asm volatile("ds_read_b128 %0, %1"
        : "=v"(r)
        : "v"((const __attribute__((address_space(3))) bf16*)p));
    return r;
}

// NT GEMM, 128x128 tile, BK=32, 4 waves, MFMA 16x16x32 (R2-proven core)
// + 3-slot LDS ring with counted-vmcnt pipeline:
//   iter t: stage tile t+2 (async global_load_lds) into slot (t+2)%3,
//           asm-ds_read fragments from slot t%3, MFMA,
//           s_waitcnt vmcnt(4) (tile t+1 landed, t+2 still flying),
//           raw s_barrier (no implicit drain).
//   Slot being staged is never read this iteration; its previous readers
//   finished last iteration (lgkmcnt(0) before MFMA, then barrier).
// LDS chunk-XOR swizzle (proven 0-conflict): slot q of row r holds global
// 16B chunk q ^ ((r>>1)&3); staging pre-swizzles the global source address.
// MODE_QKV:    C = bf16(acc + bias[col])
// MODE_SCORES: C = bf16(exp(alpha*acc))
// MODE_PV:     C = fp32 acc
template <int MODE>
__global__ __launch_bounds__(256) void mfma_nt(
    const bf16* __restrict__ A, const bf16* __restrict__ B,
    const float* __restrict__ bias, void* __restrict__ Cv,
    int K, int lda, int ldb, int ldc,
    long sA, long sB, long sC, float alpha)
{
    constexpr int SLOT = 128 * 32;   // elements per ring slot (8 KiB)

    A += (long)blockIdx.z * sA;
    B += (long)blockIdx.z * sB;

    __shared__ bf16 As[3 * SLOT] __attribute__((aligned(16)));
    __shared__ bf16 Bs[3 * SLOT] __attribute__((aligned(16)));

    const int t  = threadIdx.x;
    const int m0 = blockIdx.y * 128;
    const int n0 = blockIdx.x * 128;

    const int lane = t & 63;
    const int wave = t >> 6;
    const int wrow = (wave >> 1) * 64;
    const int wcol = (wave & 1) * 64;
    const int fr   = lane & 15;
    const int kq8  = lane >> 4;          // which 8-k chunk this lane's quad wants

    // staging decomposition: chunk c -> row r=c>>2, slot q=c&3, global k8 = q ^ ((r>>1)&3)
    const int r0 = t >> 2,         q0 = t & 3;
    const int r1 = (t + 256) >> 2, q1 = (t + 256) & 3;
    const int k80 = (q0 ^ ((r0 >> 1) & 3)) * 8;
    const int k81 = (q1 ^ ((r1 >> 1) & 3)) * 8;

    const bf16* gA0 = A + (long)(m0 + r0) * lda + k80;
    const bf16* gA1 = A + (long)(m0 + r1) * lda + k81;
    const bf16* gB0 = B + (long)(n0 + r0) * ldb + k80;
    const bf16* gB1 = B + (long)(n0 + r1) * ldb + k81;

    // per-thread fragment element-offsets within a slot (swizzle folded in)
    int offA[4], offB[4];
#pragma unroll
    for (int i = 0; i < 4; i++) {
        const int ra = wrow + i * 16 + fr;
        const int rb = wcol + i * 16 + fr;
        offA[i] = (ra * 4 + (kq8 ^ ((ra >> 1) & 3))) * 8;
        offB[i] = (rb * 4 + (kq8 ^ ((rb >> 1) & 3))) * 8;
    }

    const int NT = K / 32;

#define STAGE(tt_, ss_) do {                                               \
    const long _k = (long)(tt_) * 32;                                      \
    bf16* _as = &As[(ss_) * SLOT];                                         \
    bf16* _bs = &Bs[(ss_) * SLOT];                                         \
    gload_lds16(gA0 + _k, _as + t * 8);                                    \
    gload_lds16(gA1 + _k, _as + (t + 256) * 8);                            \
    gload_lds16(gB0 + _k, _bs + t * 8);                                    \
    gload_lds16(gB1 + _k, _bs + (t + 256) * 8);                            \
} while (0)

    f32x4 acc[4][4] = {};

    // prologue: tiles 0,1 in flight; force 0 landed, leave 1 outstanding
    STAGE(0, 0);
    STAGE(1, 1);
    asm volatile("s_waitcnt vmcnt(4)" ::: "memory");
    __builtin_amdgcn_s_barrier();

    int cs = 0;                                   // current slot = tt % 3
    for (int tt = 0; tt < NT; ++tt) {
        const int ss = (cs >= 1) ? cs - 1 : 2;    // stage slot = (tt+2) % 3
        if (tt + 2 < NT) STAGE(tt + 2, ss);

        const bf16* as = &As[cs * SLOT];
        const bf16* bs = &Bs[cs * SLOT];

        // fragment reads (asm): af0, af1, B0..B3 first, then af2, af3 so the
        // tail reads overlap the first MFMA cluster via lgkmcnt(2).
        bf16x8 af[4], bfr[4];
        af[0]  = ds_read16(as + offA[0]);
        af[1]  = ds_read16(as + offA[1]);
        bfr[0] = ds_read16(bs + offB[0]);
        bfr[1] = ds_read16(bs + offB[1]);
        bfr[2] = ds_read16(bs + offB[2]);
        bfr[3] = ds_read16(bs + offB[3]);
        af[2]  = ds_read16(as + offA[2]);
        af[3]  = ds_read16(as + offA[3]);

        asm volatile("s_waitcnt lgkmcnt(2)" ::: "memory");
        __builtin_amdgcn_sched_barrier(0);
        __builtin_amdgcn_s_setprio(1);
#pragma unroll
        for (int i = 0; i < 2; i++)
#pragma unroll
            for (int j = 0; j < 4; j++)
                acc[i][j] = __builtin_amdgcn_mfma_f32_16x16x32_bf16(
                    af[i], bfr[j], acc[i][j], 0, 0, 0);
        __builtin_amdgcn_s_setprio(0);

        asm volatile("s_waitcnt lgkmcnt(0)" ::: "memory");
        __builtin_amdgcn_sched_barrier(0);
        __builtin_amdgcn_s_setprio(1);
#pragma unroll
        for (int i = 2; i < 4; i++)
#pragma unroll
            for (int j = 0; j < 4; j++)
                acc[i][j] = __builtin_amdgcn_mfma_f32_16x16x32_bf16(
                    af[i], bfr[j], acc[i][j], 0, 0, 0);
        __builtin_amdgcn_s_setprio(0);

        // counted wait: tile t+1 must be landed; tile t+2 stays in flight.
        if (tt + 2 < NT)
            asm volatile("s_waitcnt vmcnt(4)" ::: "memory");
        else
            asm volatile("s_waitcnt vmcnt(0)" ::: "memory");
        __builtin_amdgcn_s_barrier();

        cs = (cs < 2) ? cs + 1 : 0;
    }
#undef STAGE

    // C/D layout: col=lane&15, row=(lane>>4)*4+reg  [m89-verified]
    const int r4 = (lane >> 4) * 4;
    if constexpr (MODE == MODE_PV) {
        float* C = (float*)Cv + (long)blockIdx.z * sC;
#pragma unroll
        for (int j = 0; j < 4; j++) {
            const int col = n0 + wcol + j * 16 + fr;
#pragma unroll
            for (int i = 0; i < 4; i++)
#pragma unroll
                for (int r = 0; r < 4; r++) {
                    const long row = m0 + wrow + i * 16 + r4 + r;
                    C[row * ldc + col] = acc[i][j][r];
                }
        }
    } else {
        bf16* C = (bf16*)Cv + (long)blockIdx.z * sC;
#pragma unroll
        for (int j = 0; j < 4; j++) {
            const int col = n0 + wcol + j * 16 + fr;
            const float bv = (MODE == MODE_QKV) ? bias[col] : 0.f;
#pragma unroll
            for (int i = 0; i < 4; i++)
#pragma unroll
                for (int r = 0; r < 4; r++) {
                    const long row = m0 + wrow + i * 16 + r4 + r;
                    float v = acc[i][j][r];
                    if constexpr (MODE == MODE_QKV)
                        C[row * ldc + col] = (bf16)(v + bv);
                    else
                        C[row * ldc + col] = (bf16)__expf(alpha * v);
                }
        }
    }
}

__global__ __launch_bounds__(256) void f32_to_bf16(
    const float* __restrict__ in, bf16* __restrict__ out, long n)
{
    long i = ((long)blockIdx.x * 256 + threadIdx.x) * 4;
    if (i < n) {
        float4 v = *(const float4*)(in + i);
        bf16x4 o = { (bf16)v.x, (bf16)v.y, (bf16)v.z, (bf16)v.w };
        *(bf16x4*)(out + i) = o;
    }
}

// Vt[b][e][s] = V[b][s][e]; V has ld 3072 (inside qkv), Vt ld 2048.
__global__ __launch_bounds__(256) void transpose_v(
    const bf16* __restrict__ V, bf16* __restrict__ Vt)
{
    __shared__ bf16 tile[32][33];
    const bf16* Vb  = V  + (long)blockIdx.z * 2048 * 3072;
    bf16*       Vtb = Vt + (long)blockIdx.z * 1024 * 2048;
    const int s0 = blockIdx.x * 32, e0 = blockIdx.y * 32;
    const int tx = threadIdx.x & 31, ty = threadIdx.x >> 5;
#pragma unroll
    for (int i = 0; i < 32; i += 8)
        tile[ty + i][tx] = Vb[(long)(s0 + ty + i) * 3072 + e0 + tx];
    __syncthreads();
#pragma unroll
    for (int i = 0; i < 32; i += 8)
        Vtb[(long)(e0 + ty + i) * 2048 + s0 + tx] = tile[tx][ty + i];
}

// Per row: sum exp-scores, write fp32 out1 = Pu/l, renormalize Pu IN PLACE (bf16).
__global__ __launch_bounds__(256) void norm_rows(
    bf16* __restrict__ Pu, float* __restrict__ out1)
{
    bf16* p  = Pu   + (long)blockIdx.x * 2048;
    float* o = out1 + (long)blockIdx.x * 2048;
    const int t = threadIdx.x;
    bf16x8 v = *(const bf16x8*)(p + t * 8);
    float f[8];
    float s = 0.f;
#pragma unroll
    for (int k = 0; k < 8; k++) { f[k] = (float)v[k]; s += f[k]; }
#pragma unroll
    for (int off = 32; off > 0; off >>= 1) s += __shfl_xor(s, off);
    __shared__ float red[4];
    const int wid = t >> 6, lane = t & 63;
    if (lane == 0) red[wid] = s;
    __syncthreads();
    s = red[0] + red[1] + red[2] + red[3];
    const float inv = 1.0f / s;
    float4 a, b;
    a.x = f[0] * inv; a.y = f[1] * inv; a.z = f[2] * inv; a.w = f[3] * inv;
    b.x = f[4] * inv; b.y = f[5] * inv; b.z = f[6] * inv; b.w = f[7] * inv;
    *(float4*)(o + t * 8)     = a;
    *(float4*)(o + t * 8 + 4) = b;
    bf16x8 w;
#pragma unroll
    for (int k = 0; k < 8; k++) w[k] = (bf16)(f[k] * inv);
    *(bf16x8*)(p + t * 8) = w;
}

extern "C" void kernel_launch(void* const* d_in, const int* in_sizes, int n_in,
                              void* d_out, int out_size, void* d_ws, size_t ws_size,
                              hipStream_t stream)
{
    const int B = 4, S = 2048, E = 1024;
    const float* X    = (const float*)d_in[0];   // [B,S,E]
    const float* W    = (const float*)d_in[1];   // [3E,E]
    const float* bias = (const float*)d_in[2];   // [3E]

    float* out0 = (float*)d_out;                  // [B,S,E]
    float* out1 = out0 + (long)B * S * E;         // [B,S,S]

    // ws layout (bytes):
    //   [ 0M, 48M)  qkvb bf16 [B*S, 3072]
    //   [48M, 64M)  Vt   bf16 [B][E][S]
    //   [64M, 96M)  Pu   bf16 [B][S][S]  (exp-scores; renormalized in place)
    //   Xb [64M,80M) and Wb [80M,86.3M) overlap Pu — dead before Pu is written.
    char* ws = (char*)d_ws;
    bf16* qkvb = (bf16*)(ws);
    bf16* Vt   = (bf16*)(ws + 50331648);
    bf16* Pu   = (bf16*)(ws + 67108864);
    bf16* Xb   = (bf16*)(ws + 67108864);
    bf16* Wb   = (bf16*)(ws + 83886080);

    f32_to_bf16<<<(long)B * S * E / 1024, 256, 0, stream>>>(X, Xb, (long)B * S * E);
    f32_to_bf16<<<(long)3 * E * E / 1024, 256, 0, stream>>>(W, Wb, (long)3 * E * E);

    // qkvb = bf16(X @ W^T + b)   [M=8192, N=3072, K=1024] -> 1536 blocks
    mfma_nt<MODE_QKV><<<dim3(3 * E / 128, B * S / 128, 1), 256, 0, stream>>>(
        Xb, Wb, bias, qkvb, E, E, E, 3 * E, 0, 0, 0, 1.0f);

    // Vt = V^T per batch
    transpose_v<<<dim3(S / 32, E / 32, B), 256, 0, stream>>>(qkvb + 2 * E, Vt);

    // Pu = bf16(exp(Q @ K^T / 32))  [2048x2048, K=1024] x4 -> 1024 blocks
    mfma_nt<MODE_SCORES><<<dim3(S / 128, S / 128, B), 256, 0, stream>>>(
        qkvb, qkvb + E, nullptr, Pu, E, 3 * E, 3 * E, S,
        (long)S * 3 * E, (long)S * 3 * E, (long)S * S, 0.03125f);

    // out1 = Pu / rowsum  (fp32); Pu <- normalized bf16 in place
    norm_rows<<<B * S, 256, 0, stream>>>(Pu, out1);

    // out0 = P @ V  (= Pu @ Vt^T, NT)  [2048x1024, K=2048] x4 -> 512 blocks
    mfma_nt<MODE_PV><<<dim3(E / 128, S / 128, B), 256, 0, stream>>>(
        Pu, Vt, nullptr, out0, S, S, S, E,
        (long)S * S, (long)E * S, (long)S * E, 1.0f);
}